// Round 11
// baseline (118.172 us; speedup 1.0000x reference)
//
#include <hip/hip_runtime.h>
#include <math.h>

#define NB 8
#define NP 512
#define NF 512
#define NH 64
#define NW 64
#define FEXPAND 0.02f
#define FEPS 1e-10f

#define IMG_OFF 0
#define PROB_OFF (NB*NH*NW*3)            /* 98304  */
#define NRM_OFF  (PROB_OFF + NB*NH*NW)   /* 131072 */
#define MASK_OFF (NRM_OFF + NB*NF*3)     /* 143360 */

// d_ws float layout:
//  partials SoA: comp c in 0..5 (bestz, bestf-as-float, prod, w0, w1, w2)
//    P(c,T,s,lane) = ((c*512 + T)*16 + s)*64 + lane   -> 3.1M floats (12.6MB)
//  face records at REC0 = 4Mi floats (16MB): 4096 faces x 28 floats
#define REC0 4194304

// 3-kernel pipeline, bit-identical outputs to the r10-passing kernel:
//  1) face_setup: records ONCE to d_ws (kills 512x redundant per-block setup),
//     normals to out. Same exact __f*_rn formulas as r10 (verbatim).
//  2) raster: 2048 blocks x 256 thr, __launch_bounds__(256,4) -> 128-VGPR
//     budget (r5-r10 used (1024,8) = 64-VGPR cap; r5's counter row showed
//     VGPR_Count=24 -> register-starved serialization was the hidden 3x).
//     tile T = blockIdx>>2 (8x8 px, lane=pixel), wave-slice s = (blockIdx&3)*4
//     + wave; slice scans ascending flist entries s, s+16, ... (same order as
//     r10 -> same bits). Records read from L2; bin+compact per block; partial
//     written straight to d_ws, no intra-block combine.
//  3) merge: folds 16 slices per pixel ascending with r10's exact predicate
//     (oz>bz)||(oz==bz && of<bf) and ascending prod order -> bit-identical.
// Exactness-preserving gates kept verbatim (sign-precheck == w>=0 test;
// covered -> prod=0 latch == *(1-exp(-0))).
__global__ __launch_bounds__(256, 4) void face_setup(
    const float* __restrict__ verts, const int* __restrict__ faces,
    const float* __restrict__ rot, const float* __restrict__ pos,
    const float* __restrict__ proj, float* __restrict__ ws,
    float* __restrict__ out)
{
  int t = blockIdx.x * 256 + threadIdx.x;
  if (t >= NB * NF) return;
  int b = t >> 9;
  float p0 = proj[0], p1 = proj[1], p2 = proj[2];
  float R0=rot[b*9+0],R1=rot[b*9+1],R2=rot[b*9+2];
  float R3=rot[b*9+3],R4=rot[b*9+4],R5=rot[b*9+5];
  float R6=rot[b*9+6],R7=rot[b*9+7],R8=rot[b*9+8];
  float ppx=pos[b*3+0], ppy=pos[b*3+1], ppz=pos[b*3+2];
  int idxs[3] = { faces[t*3+0], faces[t*3+1], faces[t*3+2] };
  float X[3],Y[3],Z[3],SX[3],SY[3];
#pragma unroll
  for (int k = 0; k < 3; ++k) {
    const float* v = verts + ((size_t)b*NP + idxs[k])*3;
    float dx = v[0]-ppx, dy = v[1]-ppy, dz = v[2]-ppz;
    // pcam_i = sum_j R[i][j]*(v-pos)_j, left-to-right, no FMA (verified r4..r10)
    float pcx = __fadd_rn(__fadd_rn(__fmul_rn(R0,dx),__fmul_rn(R1,dy)),__fmul_rn(R2,dz));
    float pcy = __fadd_rn(__fadd_rn(__fmul_rn(R3,dx),__fmul_rn(R4,dy)),__fmul_rn(R5,dz));
    float pcz = __fadd_rn(__fadd_rn(__fmul_rn(R6,dx),__fmul_rn(R7,dy)),__fmul_rn(R8,dz));
    X[k]=pcx; Y[k]=pcy; Z[k]=pcz;
    float dn = __fmul_rn(pcz, p2);
    SX[k] = __fdiv_rn(__fmul_rn(pcx, p0), dn);
    SY[k] = __fdiv_rn(__fmul_rn(pcy, p1), dn);
  }
  float e1x=X[1]-X[0], e1y=Y[1]-Y[0], e1z=Z[1]-Z[0];
  float e2x=X[2]-X[0], e2y=Y[2]-Y[0], e2z=Z[2]-Z[0];
  // valid gate: ELEMENTWISE nz (verified r4..r10)
  float nzel = __fsub_rn(__fmul_rn(e1x,e2y), __fmul_rn(e1y,e2x));
  // normal1 output: FMA-contracted cross (XLA golden; verified r4..r10)
  float m0 = __fmul_rn(e1z, e2y); float nxf = __fmaf_rn(e1y, e2z, -m0);
  float m1 = __fmul_rn(e1x, e2z); float nyf = __fmaf_rn(e1z, e2x, -m1);
  float m2 = __fmul_rn(e1y, e2x); float nzf = __fmaf_rn(e1x, e2y, -m2);
  float nn = __fsqrt_rn(__fadd_rn(__fadd_rn(__fmul_rn(nxf,nxf),__fmul_rn(nyf,nyf)),
                                  __fmul_rn(nzf,nzf)));
  float den = __fadd_rn(nn, 1e-12f);
  out[NRM_OFF + (size_t)t*3+0] = __fdiv_rn(nxf, den);
  out[NRM_OFF + (size_t)t*3+1] = __fdiv_rn(nyf, den);
  out[NRM_OFF + (size_t)t*3+2] = __fdiv_rn(nzf, den);

  float ax=SX[0],ay=SY[0],bx=SX[1],by=SY[1],cx=SX[2],cy=SY[2];
  float det = __fadd_rn(__fmul_rn(__fsub_rn(by,cy),__fsub_rn(ax,cx)),
                        __fmul_rn(__fsub_rn(cx,bx),__fsub_rn(ay,cy)));
  float det_safe = (fabsf(det) < FEPS) ? FEPS : det;
  float validf = ((nzel > 0.0f) && (fabsf(det) > FEPS)) ? 1.0f : 0.0f;
  float* d = ws + REC0 + (size_t)t*28;
  d[0]=__fsub_rn(by,cy); d[1]=__fsub_rn(cx,bx);
  d[2]=__fsub_rn(cy,ay); d[3]=__fsub_rn(ax,cx);
  d[4]=cx; d[5]=cy; d[6]=det_safe; d[7]=validf;
  d[8]=Z[0]; d[9]=Z[1]; d[10]=Z[2];
  float vx=bx-ax, vy=by-ay;
  d[11]=1.0f/(vx*vx+vy*vy+1e-12f);
  d[20]=vx; d[21]=vy;
  d[12]=fminf(fminf(ax,bx),cx)-FEXPAND; d[13]=fmaxf(fmaxf(ax,bx),cx)+FEXPAND;
  d[14]=fminf(fminf(ay,by),cy)-FEXPAND; d[15]=fmaxf(fmaxf(ay,by),cy)+FEXPAND;
  d[16]=ax; d[17]=ay; d[18]=bx; d[19]=by;
  vx=cx-bx; vy=cy-by;
  d[22]=vx; d[23]=vy; d[26]=1.0f/(vx*vx+vy*vy+1e-12f);
  vx=ax-cx; vy=ay-cy;
  d[24]=vx; d[25]=vy; d[27]=1.0f/(vx*vx+vy*vy+1e-12f);
}

__global__ __launch_bounds__(256, 4) void raster(
    const float* __restrict__ ws_ro, float* __restrict__ ws,
    const int* __restrict__ faces)
{
  __shared__ unsigned short flist[NF];
  __shared__ int wcnt[8];
  __shared__ int Ltot;
  int tid  = threadIdx.x;
  int T    = blockIdx.x >> 2;          // tile 0..511
  int sb   = blockIdx.x & 3;
  int wave = tid >> 6;
  int lane = tid & 63;
  int slice = sb*4 + wave;             // 0..15
  int b    = T >> 6;
  int txy  = T & 63;
  int ix0 = (txy & 7)*8, iy0 = (txy >> 3)*8;
  int ix = ix0 + (lane & 7);
  int iy = iy0 + (lane >> 3);
  // xs=(2ix+1-64)/64, ys=(64-2iy-1)/64 : all ops exact (pow2 divide)
  float x = (2.0f*ix + 1.0f - 64.0f) * (1.0f/64.0f);
  float y = (64.0f - 2.0f*iy - 1.0f) * (1.0f/64.0f);
  float txlo = (2.0f*ix0 + 1.0f - 64.0f) * (1.0f/64.0f);
  float txhi = (2.0f*(ix0+7) + 1.0f - 64.0f) * (1.0f/64.0f);
  float tyhi = (64.0f - 2.0f*iy0 - 1.0f) * (1.0f/64.0f);
  float tylo = (64.0f - 2.0f*(iy0+7) - 1.0f) * (1.0f/64.0f);
  const float* recs = ws_ro + REC0 + (size_t)b*NF*28;

  // ---- bin: 2 rounds x 4 waves, ascending face order ----
#pragma unroll
  for (int r = 0; r < 2; ++r) {
    int f = r*256 + tid;
    const float* rr = recs + (size_t)f*28 + 12;
    bool pass = (rr[1] >= txlo) && (rr[0] <= txhi) && (rr[3] >= tylo) && (rr[2] <= tyhi);
    unsigned long long m = __ballot(pass);
    if (lane == 0) wcnt[r*4 + wave] = __popcll(m);
    // stash mask bits via per-thread flag; compact after barrier
    __syncthreads();
    if (pass) {
      int gi = r*4 + wave;
      int off = 0;
#pragma unroll
      for (int i = 0; i < 8; ++i) if (i < gi) off += wcnt[i];
      off += __popcll(m & ((1ull << lane) - 1ull));
      flist[off] = (unsigned short)f;
    }
    __syncthreads();
  }
  if (tid == 0) {
    int s = 0;
#pragma unroll
    for (int i = 0; i < 8; ++i) s += wcnt[i];
    Ltot = s;
  }
  __syncthreads();
  int L = Ltot;

  float bestz = -1e10f;
  int   bestf = 0;
  float bw0 = 0.0f, bw1 = 0.0f, bw2 = 0.0f;
  float prod  = 1.0f;

  int idx = slice;
  int fcur = (idx < L) ? (int)flist[idx] : 0;
  float4 bb = (idx < L) ? *(const float4*)(recs + (size_t)fcur*28 + 12)
                        : make_float4(0.f,0.f,0.f,0.f);
  while (idx < L) {
    int nidx = idx + 16;
    int fnext = fcur;
    float4 bbn = bb;
    if (nidx < L) {
      fnext = (int)flist[nidx];
      bbn = *(const float4*)(recs + (size_t)fnext*28 + 12);
    }
    int f = fcur;
    const float* r = recs + (size_t)f*28;
    bool inb = (x >= bb.x) && (x <= bb.y) && (y >= bb.z) && (y <= bb.w);
    bool covered = false;
    if (__any(inb)) {
      float4 qe = *(const float4*)(r);       // e0x,e0y,e1x,e1y
      float4 q1 = *(const float4*)(r + 4);   // cx,cy,det_safe,validf
      float dxc = x - q1.x, dyc = y - q1.y;
      float n0 = __fadd_rn(__fmul_rn(qe.x, dxc), __fmul_rn(qe.y, dyc));
      float n1 = __fadd_rn(__fmul_rn(qe.z, dxc), __fmul_rn(qe.w, dyc));
      // exact sign-equivalent of (w0>=0 && w1>=0) (verified r9/r10)
      bool dsp  = q1.z > 0.0f;
      bool spass = ((n0 == 0.0f) || ((n0 > 0.0f) == dsp)) &&
                   ((n1 == 0.0f) || ((n1 > 0.0f) == dsp));
      bool act = inb && spass;
      if (__any(act)) {
        float4 q2 = *(const float4*)(r + 8); // za,zb,zc,invAB
        float w0 = __fdiv_rn(n0, q1.z);
        float w1 = __fdiv_rn(n1, q1.z);
        float w2 = __fsub_rn(__fsub_rn(1.0f, w0), w1);
        covered = act && (w2 >= 0.0f);
        bool valid = covered && (q1.w > 0.5f);
        float z = __fadd_rn(__fadd_rn(__fmul_rn(w0,q2.x), __fmul_rn(w1,q2.y)),
                            __fmul_rn(w2,q2.z));
        float zval = valid ? z : -1e10f;
        if (zval > bestz) { bestz = zval; bestf = f; bw0 = w0; bw1 = w1; bw2 = w2; }
      }
      if (covered) prod = 0.0f;              // == prod*(1-exp(-0)) exactly
      bool needd = inb && !covered && (prod != 0.0f);
      if (__any(needd)) {
        float4 qa = *(const float4*)(r + 16); // ax,ay,bx,by
        float4 qv = *(const float4*)(r + 20); // vABx,vABy,vBCx,vBCy
        float4 qw = *(const float4*)(r + 24); // vCAx,vCAy,invBC,invCA
        float invAB = r[11];
        float dxa = x - qa.x, dya = y - qa.y;
        float t1 = fminf(fmaxf((dxa*qv.x + dya*qv.y)*invAB, 0.0f), 1.0f);
        float rx = dxa - t1*qv.x, ry = dya - t1*qv.y;
        float d2 = rx*rx + ry*ry;
        float dxb = x - qa.z, dyb = y - qa.w;
        t1 = fminf(fmaxf((dxb*qv.z + dyb*qv.w)*qw.z, 0.0f), 1.0f);
        rx = dxb - t1*qv.z; ry = dyb - t1*qv.w;
        d2 = fminf(d2, rx*rx + ry*ry);
        t1 = fminf(fmaxf((dxc*qw.x + dyc*qw.y)*qw.w, 0.0f), 1.0f);
        rx = dxc - t1*qw.x; ry = dyc - t1*qw.y;
        d2 = fminf(d2, rx*rx + ry*ry);
        if (needd)
          prod *= (1.0f - __expf(d2 * -142.85714285714286f));  // -(1e6/7000)*d2
      }
    }
    idx = nidx; fcur = fnext; bb = bbn;
  }

  // SoA partial write (each wave owns its row; no barriers needed)
  size_t base = ((size_t)T*16 + slice)*64 + lane;
  ws[ (size_t)0*512*16*64 + base] = bestz;
  ws[ (size_t)1*512*16*64 + base] = __int_as_float(bestf);
  ws[ (size_t)2*512*16*64 + base] = prod;
  ws[ (size_t)3*512*16*64 + base] = bw0;
  ws[ (size_t)4*512*16*64 + base] = bw1;
  ws[ (size_t)5*512*16*64 + base] = bw2;
}

__global__ __launch_bounds__(256, 4) void merge(
    const float* __restrict__ ws, const int* __restrict__ faces,
    const float* __restrict__ colors, float* __restrict__ out)
{
  int gp = blockIdx.x * 256 + threadIdx.x;   // 0..32767
  int b  = gp >> 12;
  int p  = gp & 4095;
  int iy = p >> 6, ix = p & 63;
  int T  = b*64 + (iy >> 3)*8 + (ix >> 3);
  int lane = (iy & 7)*8 + (ix & 7);
  const size_t C = (size_t)512*16*64;
  size_t base = ((size_t)T*16)*64 + lane;

  float bz = ws[0*C + base]; int bf = __float_as_int(ws[1*C + base]);
  float pr = ws[2*C + base];
  float w0 = ws[3*C + base], w1 = ws[4*C + base], w2 = ws[5*C + base];
  for (int s = 1; s < 16; ++s) {
    size_t o = base + (size_t)s*64;
    float oz = ws[0*C + o]; int of = __float_as_int(ws[1*C + o]);
    if (oz > bz || (oz == bz && of < bf)) {
      bz = oz; bf = of; w0 = ws[3*C + o]; w1 = ws[4*C + o]; w2 = ws[5*C + o];
    }
    pr *= ws[2*C + o];
  }
  int av = (bz != -1e10f);       // valid faces have z in [-5,-1] >> -1e10
  int t = b * NF + bf;
  const int* fi = faces + (size_t)t*3;
  const float* cb = colors + (size_t)b*NP*3;
  int i0 = fi[0], i1 = fi[1], i2 = fi[2];
  float fr  = w0*cb[i0*3+0] + w1*cb[i1*3+0] + w2*cb[i2*3+0];
  float fgc = w0*cb[i0*3+1] + w1*cb[i1*3+1] + w2*cb[i2*3+1];
  float fb  = w0*cb[i0*3+2] + w1*cb[i1*3+2] + w2*cb[i2*3+2];
  float fa  = __fadd_rn(__fadd_rn(w0, w1), w2);
  out[IMG_OFF + (size_t)gp*3 + 0] = av ? fr  : 0.0f;
  out[IMG_OFF + (size_t)gp*3 + 1] = av ? fgc : 0.0f;
  out[IMG_OFF + (size_t)gp*3 + 2] = av ? fb  : 0.0f;
  out[PROB_OFF + gp] = 1.0f - pr;
  out[MASK_OFF + gp] = av ? fa : 0.0f;
}

extern "C" void kernel_launch(void* const* d_in, const int* in_sizes, int n_in,
                              void* d_out, int out_size, void* d_ws, size_t ws_size,
                              hipStream_t stream) {
  const float* verts  = (const float*)d_in[0];
  const int*   faces  = (const int*)  d_in[1];
  const float* rot    = (const float*)d_in[2];
  const float* pos    = (const float*)d_in[3];
  const float* proj   = (const float*)d_in[4];
  const float* colors = (const float*)d_in[5];
  float* out = (float*)d_out;
  float* ws  = (float*)d_ws;

  hipLaunchKernelGGL(face_setup, dim3((NB*NF)/256), dim3(256), 0, stream,
                     verts, faces, rot, pos, proj, ws, out);
  hipLaunchKernelGGL(raster, dim3(512*4), dim3(256), 0, stream,
                     ws, ws, faces);
  hipLaunchKernelGGL(merge, dim3((NB*NH*NW)/256), dim3(256), 0, stream,
                     ws, faces, colors, out);
}

// Round 12
// 97.488 us; speedup vs baseline: 1.2122x; 1.2122x over previous
//
#include <hip/hip_runtime.h>
#include <math.h>

#define NB 8
#define NP 512
#define NF 512
#define NH 64
#define NW 64
#define FEXPAND 0.02f
#define FEPS 1e-10f

#define IMG_OFF 0
#define PROB_OFF (NB*NH*NW*3)            /* 98304  */
#define NRM_OFF  (PROB_OFF + NB*NH*NW)   /* 131072 */
#define MASK_OFF (NRM_OFF + NB*NF*3)     /* 143360 */

// r10 structure (best measured: dur 89.5) with ONE change: the face scan is a
// 2-deep SOFTWARE PIPELINE. r10's loop demand-read flist -> 4 ds_reads -> div
// chain serially each iteration (~120cy LDS latency exposed several times);
// r11 proved the work itself is only ~10us (VALUBusy 20% of 46us) -- stalls
// dominate. Here face i's full hot record (qe,q1,q2,bbox) is in registers
// while face i+16's loads are in flight (issued one body (~250cy) ahead).
// Computation order and every arithmetic op are UNCHANGED -> bit-identical.
// Exactness invariants (verified r4..r10):
//  - pcam/screen/det/valid: exact __f*_rn, no FMA
//  - normal1: FMA-contracted cross n_i = fmaf(a1,b2,-fl(a2*b1)) (XLA golden)
//  - sign-precheck == (w0>=0 && w1>=0) exactly; covered -> prod=0 latch
//  - winner w0/w1/w2 saved at z-update; av == (bestz != -1e10f)
// Record: 28 floats (112 B):
//  [0..3] e0x,e0y,e1x,e1y  [4..7] cx,cy,det_safe,validf  [8..11] za,zb,zc,invAB
//  [12..15] xmin,xmax,ymin,ymax  [16..19] ax,ay,bx,by
//  [20..23] vABx,vABy,vBCx,vBCy  [24..27] vCAx,vCAy,invBC,invCA
__global__ __launch_bounds__(1024, 8) void render_all(
    const float* __restrict__ verts, const int* __restrict__ faces,
    const float* __restrict__ rot, const float* __restrict__ pos,
    const float* __restrict__ proj, const float* __restrict__ colors,
    float* __restrict__ out)
{
  __shared__ __align__(16) float smem[NF*28];   // 56 KiB; combine buf aliased
  __shared__ unsigned short flist[NF];
  __shared__ int wcnt[8];
  __shared__ int Ltot;
  int tid  = threadIdx.x;
  int b    = blockIdx.x >> 6;    // 64 tiles per batch
  int tile = blockIdx.x & 63;
  int wave = tid >> 6;           // 16 waves
  int lane = tid & 63;           // pixel within 8x8 tile
  int ix0 = (tile & 7)*8, iy0 = (tile >> 3)*8;
  int ix = ix0 + (lane & 7);
  int iy = iy0 + (lane >> 3);
  // xs=(2ix+1-64)/64, ys=(64-2iy-1)/64 : all ops exact (pow2 divide)
  float x = (2.0f*ix + 1.0f - 64.0f) * (1.0f/64.0f);
  float y = (64.0f - 2.0f*iy - 1.0f) * (1.0f/64.0f);
  // tile pixel-center rect (exact)
  float txlo = (2.0f*ix0 + 1.0f - 64.0f) * (1.0f/64.0f);
  float txhi = (2.0f*(ix0+7) + 1.0f - 64.0f) * (1.0f/64.0f);
  float tyhi = (64.0f - 2.0f*iy0 - 1.0f) * (1.0f/64.0f);
  float tylo = (64.0f - 2.0f*(iy0+7) - 1.0f) * (1.0f/64.0f);

  if (tid < NF) {
    int t = b * NF + tid;
    float p0 = proj[0], p1 = proj[1], p2 = proj[2];
    float R0=rot[b*9+0],R1=rot[b*9+1],R2=rot[b*9+2];
    float R3=rot[b*9+3],R4=rot[b*9+4],R5=rot[b*9+5];
    float R6=rot[b*9+6],R7=rot[b*9+7],R8=rot[b*9+8];
    float ppx=pos[b*3+0], ppy=pos[b*3+1], ppz=pos[b*3+2];
    int idxs[3] = { faces[t*3+0], faces[t*3+1], faces[t*3+2] };
    float X[3],Y[3],Z[3],SX[3],SY[3];
#pragma unroll
    for (int k = 0; k < 3; ++k) {
      const float* v = verts + ((size_t)b*NP + idxs[k])*3;
      float dx = v[0]-ppx, dy = v[1]-ppy, dz = v[2]-ppz;
      float pcx = __fadd_rn(__fadd_rn(__fmul_rn(R0,dx),__fmul_rn(R1,dy)),__fmul_rn(R2,dz));
      float pcy = __fadd_rn(__fadd_rn(__fmul_rn(R3,dx),__fmul_rn(R4,dy)),__fmul_rn(R5,dz));
      float pcz = __fadd_rn(__fadd_rn(__fmul_rn(R6,dx),__fmul_rn(R7,dy)),__fmul_rn(R8,dz));
      X[k]=pcx; Y[k]=pcy; Z[k]=pcz;
      float dn = __fmul_rn(pcz, p2);
      SX[k] = __fdiv_rn(__fmul_rn(pcx, p0), dn);
      SY[k] = __fdiv_rn(__fmul_rn(pcy, p1), dn);
    }
    float e1x=X[1]-X[0], e1y=Y[1]-Y[0], e1z=Z[1]-Z[0];
    float e2x=X[2]-X[0], e2y=Y[2]-Y[0], e2z=Z[2]-Z[0];
    float nzel = __fsub_rn(__fmul_rn(e1x,e2y), __fmul_rn(e1y,e2x));
    if (tile == 0) {
      float m0 = __fmul_rn(e1z, e2y); float nxf = __fmaf_rn(e1y, e2z, -m0);
      float m1 = __fmul_rn(e1x, e2z); float nyf = __fmaf_rn(e1z, e2x, -m1);
      float m2 = __fmul_rn(e1y, e2x); float nzf = __fmaf_rn(e1x, e2y, -m2);
      float nn = __fsqrt_rn(__fadd_rn(__fadd_rn(__fmul_rn(nxf,nxf),__fmul_rn(nyf,nyf)),
                                      __fmul_rn(nzf,nzf)));
      float den = __fadd_rn(nn, 1e-12f);
      out[NRM_OFF + (size_t)t*3+0] = __fdiv_rn(nxf, den);
      out[NRM_OFF + (size_t)t*3+1] = __fdiv_rn(nyf, den);
      out[NRM_OFF + (size_t)t*3+2] = __fdiv_rn(nzf, den);
    }
    float ax=SX[0],ay=SY[0],bx=SX[1],by=SY[1],cx=SX[2],cy=SY[2];
    float det = __fadd_rn(__fmul_rn(__fsub_rn(by,cy),__fsub_rn(ax,cx)),
                          __fmul_rn(__fsub_rn(cx,bx),__fsub_rn(ay,cy)));
    float det_safe = (fabsf(det) < FEPS) ? FEPS : det;
    float validf = ((nzel > 0.0f) && (fabsf(det) > FEPS)) ? 1.0f : 0.0f;
    float* d = &smem[tid*28];
    d[0]=__fsub_rn(by,cy); d[1]=__fsub_rn(cx,bx);
    d[2]=__fsub_rn(cy,ay); d[3]=__fsub_rn(ax,cx);
    d[4]=cx; d[5]=cy; d[6]=det_safe; d[7]=validf;
    d[8]=Z[0]; d[9]=Z[1]; d[10]=Z[2];
    float vx=bx-ax, vy=by-ay;
    d[11]=1.0f/(vx*vx+vy*vy+1e-12f);
    d[20]=vx; d[21]=vy;
    d[12]=fminf(fminf(ax,bx),cx)-FEXPAND; d[13]=fmaxf(fmaxf(ax,bx),cx)+FEXPAND;
    d[14]=fminf(fminf(ay,by),cy)-FEXPAND; d[15]=fmaxf(fmaxf(ay,by),cy)+FEXPAND;
    d[16]=ax; d[17]=ay; d[18]=bx; d[19]=by;
    vx=cx-bx; vy=cy-by;
    d[22]=vx; d[23]=vy; d[26]=1.0f/(vx*vx+vy*vy+1e-12f);
    vx=ax-cx; vy=ay-cy;
    d[24]=vx; d[25]=vy; d[27]=1.0f/(vx*vx+vy*vy+1e-12f);
  }
  __syncthreads();

  // ---- per-tile binning (threads 0..511, ascending compaction) ----
  bool pass = false;
  if (tid < NF) {
    const float* rr = &smem[tid*28 + 12];   // xmin,xmax,ymin,ymax
    pass = (rr[1] >= txlo) && (rr[0] <= txhi) && (rr[3] >= tylo) && (rr[2] <= tyhi);
  }
  unsigned long long m = __ballot(pass);
  if (tid < NF && (tid & 63) == 0) wcnt[tid >> 6] = __popcll(m);
  __syncthreads();
  if (tid < NF && pass) {
    int w8 = tid >> 6;
    int off = 0;
#pragma unroll
    for (int i = 0; i < 8; ++i) if (i < w8) off += wcnt[i];
    off += __popcll(m & ((1ull << (tid & 63)) - 1ull));
    flist[off] = (unsigned short)tid;
  }
  if (tid == 0) {
    int s = 0;
#pragma unroll
    for (int i = 0; i < 8; ++i) s += wcnt[i];
    Ltot = s;
  }
  __syncthreads();
  int L = Ltot;

  float bestz = -1e10f;
  int   bestf = 0;
  float bw0 = 0.0f, bw1 = 0.0f, bw2 = 0.0f;
  float prod  = 1.0f;

  // ---- 2-deep software-pipelined scan (same order/ops as r10) ----
  int idx = wave;
  int f0 = 0, f1 = 0;
  float4 qe0, q10, q20, bb0, qe1, q11, q21, bb1;
  if (idx < L) {
    f0 = (int)flist[idx];
    const float* r0 = &smem[f0*28];
    qe0 = *(const float4*)(r0);     q10 = *(const float4*)(r0 + 4);
    q20 = *(const float4*)(r0 + 8); bb0 = *(const float4*)(r0 + 12);
  }
  if (idx + 16 < L) {
    f1 = (int)flist[idx + 16];
    const float* r1 = &smem[f1*28];
    qe1 = *(const float4*)(r1);     q11 = *(const float4*)(r1 + 4);
    q21 = *(const float4*)(r1 + 8); bb1 = *(const float4*)(r1 + 12);
  }
  while (idx < L) {
    int i2 = idx + 32;
    bool has2 = (i2 < L);
    unsigned short f2v = has2 ? flist[i2] : (unsigned short)0;  // in flight early
    int f = f0;
    const float* r = &smem[f*28];
    bool inb = (x >= bb0.x) && (x <= bb0.y) && (y >= bb0.z) && (y <= bb0.w);
    bool covered = false;
    float dxc = x - q10.x, dyc = y - q10.y;
    if (__any(inb)) {
      float n0 = __fadd_rn(__fmul_rn(qe0.x, dxc), __fmul_rn(qe0.y, dyc));
      float n1 = __fadd_rn(__fmul_rn(qe0.z, dxc), __fmul_rn(qe0.w, dyc));
      // exact sign-equivalent of (w0>=0 && w1>=0) (verified r9/r10)
      bool dsp  = q10.z > 0.0f;
      bool spass = ((n0 == 0.0f) || ((n0 > 0.0f) == dsp)) &&
                   ((n1 == 0.0f) || ((n1 > 0.0f) == dsp));
      bool act = inb && spass;
      if (__any(act)) {
        float w0 = __fdiv_rn(n0, q10.z);
        float w1 = __fdiv_rn(n1, q10.z);
        float w2 = __fsub_rn(__fsub_rn(1.0f, w0), w1);
        covered = act && (w2 >= 0.0f);
        bool valid = covered && (q10.w > 0.5f);
        float z = __fadd_rn(__fadd_rn(__fmul_rn(w0,q20.x), __fmul_rn(w1,q20.y)),
                            __fmul_rn(w2,q20.z));
        float zval = valid ? z : -1e10f;
        if (zval > bestz) { bestz = zval; bestf = f; bw0 = w0; bw1 = w1; bw2 = w2; }
      }
      if (covered) prod = 0.0f;              // == prod*(1-exp(-0)) exactly
      bool needd = inb && !covered && (prod != 0.0f);
      if (__any(needd)) {
        float4 qa = *(const float4*)(r + 16); // ax,ay,bx,by
        float4 qv = *(const float4*)(r + 20); // vABx,vABy,vBCx,vBCy
        float4 qw = *(const float4*)(r + 24); // vCAx,vCAy,invBC,invCA
        float invAB = r[11];
        float dxa = x - qa.x, dya = y - qa.y;
        float t1 = fminf(fmaxf((dxa*qv.x + dya*qv.y)*invAB, 0.0f), 1.0f);
        float rx = dxa - t1*qv.x, ry = dya - t1*qv.y;
        float d2 = rx*rx + ry*ry;
        float dxb = x - qa.z, dyb = y - qa.w;
        t1 = fminf(fmaxf((dxb*qv.z + dyb*qv.w)*qw.z, 0.0f), 1.0f);
        rx = dxb - t1*qv.z; ry = dyb - t1*qv.w;
        d2 = fminf(d2, rx*rx + ry*ry);
        t1 = fminf(fmaxf((dxc*qw.x + dyc*qw.y)*qw.w, 0.0f), 1.0f);
        rx = dxc - t1*qw.x; ry = dyc - t1*qw.y;
        d2 = fminf(d2, rx*rx + ry*ry);
        if (needd)
          prod *= (1.0f - __expf(d2 * -142.85714285714286f));  // -(1e6/7000)*d2
      }
    }
    // shift pipeline; issue loads for face idx+32 (consumed in 2 iterations)
    idx += 16;
    f0 = f1; qe0 = qe1; q10 = q11; q20 = q21; bb0 = bb1;
    if (has2) {
      f1 = (int)f2v;
      const float* r1 = &smem[f1*28];
      qe1 = *(const float4*)(r1);     q11 = *(const float4*)(r1 + 4);
      q21 = *(const float4*)(r1 + 8); bb1 = *(const float4*)(r1 + 12);
    }
  }

  __syncthreads();                 // records dead; alias combine buffer
  float* comb = smem;              // [16 slices][64 px][stride 7] = 28 KiB
  float* c = comb + (size_t)(wave*64 + lane)*7;
  c[0]=bestz; c[1]=__int_as_float(bestf); c[2]=prod;
  c[3]=bw0; c[4]=bw1; c[5]=bw2;
  __syncthreads();

  if (tid < 64) {
    const float* c0 = comb + (size_t)tid*7;
    float bz = c0[0]; int bf = __float_as_int(c0[1]); float pr = c0[2];
    float w0 = c0[3], w1 = c0[4], w2 = c0[5];
    for (int s = 1; s < 16; ++s) {
      const float* cs = comb + (size_t)(s*64 + tid)*7;
      float oz = cs[0]; int of = __float_as_int(cs[1]);
      if (oz > bz || (oz == bz && of < bf)) { bz = oz; bf = of; w0 = cs[3]; w1 = cs[4]; w2 = cs[5]; }
      pr *= cs[2];
    }
    int av = (bz != -1e10f);       // valid faces have z >> -1e10 (z in [-5,-1])
    int t = b * NF + bf;
    const int* fi = faces + (size_t)t*3;
    const float* cb = colors + (size_t)b*NP*3;
    int i0 = fi[0], i1 = fi[1], i2 = fi[2];
    float fr  = w0*cb[i0*3+0] + w1*cb[i1*3+0] + w2*cb[i2*3+0];
    float fgc = w0*cb[i0*3+1] + w1*cb[i1*3+1] + w2*cb[i2*3+1];
    float fb  = w0*cb[i0*3+2] + w1*cb[i1*3+2] + w2*cb[i2*3+2];
    float fa  = __fadd_rn(__fadd_rn(w0, w1), w2);
    int gp = b*4096 + iy*64 + ix;  // own lane's pixel (tid<64 -> wave 0)
    out[IMG_OFF + (size_t)gp*3 + 0] = av ? fr  : 0.0f;
    out[IMG_OFF + (size_t)gp*3 + 1] = av ? fgc : 0.0f;
    out[IMG_OFF + (size_t)gp*3 + 2] = av ? fb  : 0.0f;
    out[PROB_OFF + gp] = 1.0f - pr;
    out[MASK_OFF + gp] = av ? fa : 0.0f;
  }
}

extern "C" void kernel_launch(void* const* d_in, const int* in_sizes, int n_in,
                              void* d_out, int out_size, void* d_ws, size_t ws_size,
                              hipStream_t stream) {
  const float* verts  = (const float*)d_in[0];
  const int*   faces  = (const int*)  d_in[1];
  const float* rot    = (const float*)d_in[2];
  const float* pos    = (const float*)d_in[3];
  const float* proj   = (const float*)d_in[4];
  const float* colors = (const float*)d_in[5];
  float* out = (float*)d_out;
  (void)d_ws; (void)ws_size;

  hipLaunchKernelGGL(render_all, dim3(NB*64), dim3(1024), 0, stream,
                     verts, faces, rot, pos, proj, colors, out);
}